// Round 7
// baseline (161.109 us; speedup 1.0000x reference)
//
#include <hip/hip_runtime.h>
#include <hip/hip_bf16.h>

typedef __attribute__((ext_vector_type(8))) short short8;
typedef __attribute__((ext_vector_type(4))) float f32x4;
typedef __attribute__((ext_vector_type(4))) unsigned int u32x4;

struct XPtrs { const float* p[17]; };
struct Bases { int v[18]; };

#define CPB 8  // units (of 64 rows) per block; 8 | 128*L so no tails

__device__ __forceinline__ unsigned short f2bf(float f) {
  unsigned u = __float_as_uint(f);
  return (unsigned short)((u + 0x7fffu + ((u >> 16) & 1u)) >> 16);  // RNE
}

// ---------------- pre-kernel: W fp32 -> bf16, fragment-packed into ws ----
// Per diag d: 2048 slots of 16 B. slot = sg*128 + n  (sg = s*4 + g)
// slot holds W[d][n][k] for k = sg*8 .. sg*8+7 as 8 bf16 (RNE).
__global__ __launch_bounds__(1024) void convert_w_kernel(
    const float* __restrict__ W, unsigned short* __restrict__ ws) {
  const int tid = blockIdx.x * 1024 + threadIdx.x;  // 0 .. 17*2048-1
  const int d  = tid >> 11;
  const int s2 = tid & 2047;
  const int sg = s2 >> 7;     // 0..15
  const int n  = s2 & 127;
  const float* src = W + ((size_t)d * 128 + n) * 128 + sg * 8;
  float4 a = *(const float4*)(src);
  float4 b = *(const float4*)(src + 4);
  unsigned u0 = (unsigned)f2bf(a.x) | ((unsigned)f2bf(a.y) << 16);
  unsigned u1 = (unsigned)f2bf(a.z) | ((unsigned)f2bf(a.w) << 16);
  unsigned u2 = (unsigned)f2bf(b.x) | ((unsigned)f2bf(b.y) << 16);
  unsigned u3 = (unsigned)f2bf(b.z) | ((unsigned)f2bf(b.w) << 16);
  *(uint4*)(ws + (size_t)tid * 8) = make_uint4(u0, u1, u2, u3);
}

// pack two fp32 (lo, hi) -> one u32 of two bf16, round-half-up + v_perm
__device__ __forceinline__ unsigned pack_bf2(float lo, float hi) {
  unsigned rl = __float_as_uint(lo) + 0x8000u;
  unsigned rh = __float_as_uint(hi) + 0x8000u;
  return __builtin_amdgcn_perm(rh, rl, 0x07060302u);  // {rh[31:16], rl[31:16]}
}

__device__ __forceinline__ void issue_unit_loads(
    const float* __restrict__ x, int u, int wave, int lr, int lg,
    float4 (&pf)[8]) {
  const float* xr = x + ((size_t)(u * 64 + wave * 16 + lr)) * 128 + lg * 8;
#pragma unroll
  for (int s = 0; s < 4; ++s) {
    pf[2 * s]     = *(const float4*)(xr + s * 32);
    pf[2 * s + 1] = *(const float4*)(xr + s * 32 + 4);
  }
}

__device__ __forceinline__ void convert_unit(const float4 (&pf)[8],
                                             short8 (&xf)[4]) {
#pragma unroll
  for (int s = 0; s < 4; ++s) {
    float4 a0 = pf[2 * s], a1 = pf[2 * s + 1];
    u32x4 w;
    w.x = pack_bf2(a0.x, a0.y);
    w.y = pack_bf2(a0.z, a0.w);
    w.z = pack_bf2(a1.x, a1.y);
    w.w = pack_bf2(a1.z, a1.w);
    xf[s] = __builtin_bit_cast(short8, w);
  }
}

// ---------------- main kernel ----------------
// 256 threads = 4 waves. Block owns CPB units of 64 rows in ONE diagonal.
// W+bias staged to LDS once. Steady state: 2-deep double-buffered register
// prefetch (pA/pB) -> every load batch has ~2 units of compute to hide under.
__global__ __launch_bounds__(256) void diag_linear_kernel(
    XPtrs xp, Bases bb, const unsigned short* __restrict__ wsrc,
    const float* __restrict__ bias, float* __restrict__ out) {
  const int bid = blockIdx.x;
  int d = 0;
#pragma unroll
  for (int i = 1; i < 17; ++i) d += (bid >= bb.v[i]) ? 1 : 0;
  const int L = 9 - ((d < 8) ? (8 - d) : (d - 8));
  const int start = (d > 8) ? (d - 8) : 0;
  const float* __restrict__ x = xp.p[d];
  const int u0 = (bid - bb.v[d]) * CPB;

  const int t = threadIdx.x;
  const int lane = t & 63;
  const int wave = t >> 6;       // 0..3
  const int lr = lane & 15;
  const int lg = lane >> 4;

  __shared__ unsigned short wlds[2048 * 8];  // 32 KiB
  __shared__ float blds[128];                // bias

  // ---- stage W[d] (pre-packed bf16) + bias via async global->LDS ----
  {
    const unsigned short* gw = wsrc + (size_t)d * 16384;
    typedef const __attribute__((address_space(1))) unsigned int* gas_u32;
    typedef __attribute__((address_space(3))) unsigned int* las_u32;
#pragma unroll
    for (int r = 0; r < 8; ++r) {
      const int slotbase = (wave * 8 + r) * 64;
      __builtin_amdgcn_global_load_lds(
          (gas_u32)(const void*)(gw + (size_t)(slotbase + lane) * 8),
          (las_u32)(void*)(wlds + (size_t)slotbase * 8),
          16, 0, 0);
    }
    if (t < 32) {  // lanes 0..31 -> blds[0..127], 16B/lane
      __builtin_amdgcn_global_load_lds(
          (gas_u32)(const void*)(bias + d * 128 + t * 4),
          (las_u32)(void*)(blds), 16, 0, 0);
    }
  }

  // ---- prologue: 2 units in flight (overlaps W staging) ----
  float4 pA[8], pB[8];
  issue_unit_loads(x, u0,     wave, lr, lg, pA);
  issue_unit_loads(x, u0 + 1, wave, lr, lg, pB);

  __syncthreads();   // W + bias resident

  const int npair = CPB / 2;   // nunits = 128*L is divisible by CPB: no tails
#pragma unroll
  for (int k = 0; k < npair; ++k) {
#pragma unroll
    for (int ph = 0; ph < 2; ++ph) {       // ph 0 = A-buffer, 1 = B-buffer
      const int u = u0 + 2 * k + ph;

      short8 xf[4];
      if (ph == 0) convert_unit(pA, xf);
      else         convert_unit(pB, xf);

      // reissue this buffer for unit u+2 (early: hides under MFMA+stores
      // of THIS unit and everything in the next phase)
      if (k + 1 < npair) {
        if (ph == 0) issue_unit_loads(x, u + 2, wave, lr, lg, pA);
        else         issue_unit_loads(x, u + 2, wave, lr, lg, pB);
      }

      // acc init = bias (from LDS; lane quad = couts nb*16+lg*4+0..3)
      f32x4 acc[8];
#pragma unroll
      for (int nb = 0; nb < 8; ++nb)
        acc[nb] = *(const f32x4*)&blds[nb * 16 + lg * 4];

      // MFMA: A = W frag (couts), B = X frag (16 batch rows)
#pragma unroll
      for (int s = 0; s < 4; ++s) {
#pragma unroll
        for (int nb = 0; nb < 8; ++nb) {
          short8 wf = *(const short8*)
              &wlds[(size_t)((s * 4 + lg) * 128 + nb * 16 + lr) * 8];
          acc[nb] = __builtin_amdgcn_mfma_f32_16x16x32_bf16(wf, xf[s], acc[nb], 0, 0, 0);
        }
      }

      // epilogue: D[cout = nb*16+lg*4+v][brow = lr]; 512B contiguous per row
      const int f = u * 64 + wave * 16 + lr;
      const unsigned b = (unsigned)f / (unsigned)L;
      const int l = f - (int)b * L;
      float* orow = out + (size_t)b * 10368 + (size_t)(start * 8 + d) * 128
                    + (size_t)l * 1024 + lg * 4;
#pragma unroll
      for (int nb = 0; nb < 8; ++nb)
        *(f32x4*)(orow + nb * 16) = acc[nb];
    }
  }
}

extern "C" void kernel_launch(void* const* d_in, const int* in_sizes, int n_in,
                              void* d_out, int out_size, void* d_ws, size_t ws_size,
                              hipStream_t stream) {
  const float* W = (const float*)d_in[0];
  const float* bias = (const float*)d_in[1];
  XPtrs xp;
  for (int i = 0; i < 17; ++i) xp.p[i] = (const float*)d_in[2 + i];
  float* out = (float*)d_out;
  unsigned short* ws = (unsigned short*)d_ws;   // 17*2048*16 B = 544 KiB

  Bases bb;
  int base = 0;
  for (int i = 0; i < 17; ++i) {
    bb.v[i] = base;
    int L = 9 - ((i < 8) ? (8 - i) : (i - 8));
    base += (128 * L) / CPB;     // exact: 16*L blocks per diag
  }
  bb.v[17] = base;               // 1296 blocks

  convert_w_kernel<<<34, 1024, 0, stream>>>(W, ws);
  diag_linear_kernel<<<base, 256, 0, stream>>>(xp, bb, ws, bias, out);
}